// Round 9
// baseline (497.957 us; speedup 1.0000x reference)
//
#include <hip/hip_runtime.h>

namespace {
constexpr int kB = 512;
constexpr int kT = 200;
constexpr int kI = 784;
constexpr int kH = 128;
constexpr int kO = 10;
constexpr int kM = kB * kT;  // 102400 rows
constexpr float kBeta = 0.9f;
constexpr float kThr = 1.0f;
constexpr int kSplitK0 = 400;  // 784 = 400 + 384, both % 16 == 0
}  // namespace

// ---------------------------------------------------------------------------
// C[M][128] = A[M][K-slice] . B[128][K-slice]^T (+ bias).
// 128x128 tile, 128 threads (16 m-groups x 8 n-groups), 8x16 per-thread
// register tile.  Round-8 diagnosis: LDS read pipe was the wall (8x8 tile =
// 0.25 LDS dw/FMA -> 60% VALUBusy ceiling).  8x16 -> 0.1875 dw/FMA.
// B-tile rows padded +4 per 16 columns (160-dword rows): the 8 tn-groups'
// ds_read_b128 start banks {0,20,8,28,16,4,24,12} -> conflict-free.
// Same proven skeleton otherwise: single LDS buffer, two barriers/step,
// nothing live across barriers except acc. Per-output k-order unchanged.
// ---------------------------------------------------------------------------
template <int KSTRIDE, int SPLIT>
__global__ __launch_bounds__(128, 2) void gemm8x16(
    const float* __restrict__ A, const float* __restrict__ B,
    const float* __restrict__ bias, float* __restrict__ C, size_t coff) {
  constexpr int BM = 128, BK = 16;
  constexpr int BROW = 160;  // 128 cols + 4 pad per 16 -> swz(n)=n+((n>>4)<<2)
  __shared__ float As[BK][132];
  __shared__ float Bs[BK][BROW];
  const int tid = threadIdx.x;
  const int tn = tid & 7;    // n-group 0..7  (16 cols each)
  const int tm = tid >> 3;   // m-group 0..15 (8 rows each)
  int tile, kbeg, nsteps;
  if (SPLIT) {
    tile = blockIdx.x >> 1;
    const int half = blockIdx.x & 1;
    kbeg = half ? kSplitK0 : 0;
    nsteps = half ? (KSTRIDE - kSplitK0) / BK : kSplitK0 / BK;
    if (half) C += coff;
  } else {
    tile = blockIdx.x;
    kbeg = 0;
    nsteps = KSTRIDE / BK;
  }
  const int row0 = tile * BM;

  // Staging decode: A-tile 128r x 16k = 512 float4 / 128 thr = 4 each;
  // B-tile likewise. sr = tid>>2 (+32 per l), sc4 = (tid&3)*4.
  const int sr = tid >> 2;         // 0..31
  const int sc4 = (tid & 3) * 4;   // 0,4,8,12

  const float* aptr = A + (size_t)(row0 + sr) * KSTRIDE + kbeg + sc4;
  const float* bptr = B + (size_t)sr * KSTRIDE + kbeg + sc4;

  float acc[8][16];
#pragma unroll
  for (int i = 0; i < 8; ++i)
#pragma unroll
    for (int j = 0; j < 16; ++j) acc[i][j] = 0.0f;

  for (int s = 0; s < nsteps; ++s) {
    const int k0 = s * BK;
    __syncthreads();
#pragma unroll
    for (int l = 0; l < 4; ++l) {
      const int r = sr + l * 32;
      const float4 va = *reinterpret_cast<const float4*>(
          aptr + (size_t)l * 32 * KSTRIDE + k0);
      As[sc4 + 0][r] = va.x; As[sc4 + 1][r] = va.y;
      As[sc4 + 2][r] = va.z; As[sc4 + 3][r] = va.w;
      const float4 vb = *reinterpret_cast<const float4*>(
          bptr + (size_t)l * 32 * KSTRIDE + k0);
      const int rs = r + ((r >> 4) << 2);  // swizzled B column
      Bs[sc4 + 0][rs] = vb.x; Bs[sc4 + 1][rs] = vb.y;
      Bs[sc4 + 2][rs] = vb.z; Bs[sc4 + 3][rs] = vb.w;
    }
    __syncthreads();
#pragma unroll 4
    for (int kk = 0; kk < BK; ++kk) {
      float a[8], b[16];
      *reinterpret_cast<float4*>(&a[0]) =
          *reinterpret_cast<const float4*>(&As[kk][tm * 8]);
      *reinterpret_cast<float4*>(&a[4]) =
          *reinterpret_cast<const float4*>(&As[kk][tm * 8 + 4]);
#pragma unroll
      for (int q = 0; q < 4; ++q)
        *reinterpret_cast<float4*>(&b[q * 4]) =
            *reinterpret_cast<const float4*>(&Bs[kk][tn * 20 + q * 4]);
#pragma unroll
      for (int i = 0; i < 8; ++i)
#pragma unroll
        for (int j = 0; j < 16; ++j)
          acc[i][j] = fmaf(a[i], b[j], acc[i][j]);
    }
  }

#pragma unroll
  for (int i = 0; i < 8; ++i) {
    const size_t r = (size_t)(row0 + tm * 8 + i);
#pragma unroll
    for (int q = 0; q < 4; ++q) {
      const int n = tn * 16 + q * 4;
      float4 v;
      v.x = acc[i][q * 4 + 0];
      v.y = acc[i][q * 4 + 1];
      v.z = acc[i][q * 4 + 2];
      v.w = acc[i][q * 4 + 3];
      if (bias != nullptr) {
        v.x += bias[n + 0];
        v.y += bias[n + 1];
        v.z += bias[n + 2];
        v.w += bias[n + 3];
      }
      *reinterpret_cast<float4*>(&C[r * 128 + n]) = v;
    }
  }
}

// ---------------------------------------------------------------------------
// Layer-1 LIF scan + partial combine: cur = (P0+P1) + b1; spikes -> P0.
// _rn op order matches numpy exactly; combine order proven in r7/r8.
// ---------------------------------------------------------------------------
__global__ __launch_bounds__(256) void lif_scan13(
    float* __restrict__ P0, const float* __restrict__ P1,
    const float* __restrict__ b1) {
  const int g = blockIdx.x * 256 + threadIdx.x;  // 0..65535
  const int b = g >> 7;
  const int h = g & 127;
  const size_t base = (size_t)b * kT * 128 + h;
  const float bb = b1[h];
  float m = 0.0f, s = 0.0f;
#pragma unroll 4
  for (int t = 0; t < kT; ++t) {
    const size_t idx = base + (size_t)t * 128;
    const float cur = __fadd_rn(__fadd_rn(P0[idx], P1[idx]), bb);
    m = __fsub_rn(__fadd_rn(__fmul_rn(kBeta, m), cur), s);
    s = (m > kThr) ? 1.0f : 0.0f;
    P0[idx] = s;
  }
}

// ---------------------------------------------------------------------------
// Layer-2 LIF scan, in place (bias already applied by GEMM2).
// ---------------------------------------------------------------------------
__global__ __launch_bounds__(256) void lif_scan2(float* __restrict__ buf) {
  const int g = blockIdx.x * 256 + threadIdx.x;  // 0..65535
  const int b = g >> 7;
  const int h = g & 127;
  const size_t base = (size_t)b * kT * 128 + h;
  float m = 0.0f, s = 0.0f;
#pragma unroll 4
  for (int t = 0; t < kT; ++t) {
    const size_t idx = base + (size_t)t * 128;
    m = __fsub_rn(__fadd_rn(__fmul_rn(kBeta, m), buf[idx]), s);
    s = (m > kThr) ? 1.0f : 0.0f;
    buf[idx] = s;
  }
}

// ---------------------------------------------------------------------------
// GEMM3: cur3[M][10] = s2[M][128] . W3[10][128]^T + b3. 64 rows / block,
// 320 threads, A-tile + W3 staged in LDS, 2 outputs per thread.
// ---------------------------------------------------------------------------
__global__ __launch_bounds__(320) void gemm3_n10(
    const float* __restrict__ A, const float* __restrict__ W3,
    const float* __restrict__ b3, float* __restrict__ C) {
  __shared__ float Ss[64][132];
  __shared__ float Ws[10][132];
  __shared__ float bs[10];
  const int tid = threadIdx.x;
  const size_t row0 = (size_t)blockIdx.x * 64;

  {  // stage W3: 10*128 floats = 320 float4, exactly one per thread
    const int r = tid >> 5;
    const int c4 = (tid & 31) * 4;
    const float4 v = *reinterpret_cast<const float4*>(&W3[r * 128 + c4]);
    Ws[r][c4 + 0] = v.x;
    Ws[r][c4 + 1] = v.y;
    Ws[r][c4 + 2] = v.z;
    Ws[r][c4 + 3] = v.w;
    if (tid < 10) bs[tid] = b3[tid];
  }
  for (int fi = tid; fi < 2048; fi += 320) {  // 64 rows * 32 float4
    const int r = fi >> 5;
    const int c4 = (fi & 31) * 4;
    const float4 v =
        *reinterpret_cast<const float4*>(&A[(row0 + r) * 128 + c4]);
    Ss[r][c4 + 0] = v.x;
    Ss[r][c4 + 1] = v.y;
    Ss[r][c4 + 2] = v.z;
    Ss[r][c4 + 3] = v.w;
  }
  __syncthreads();

#pragma unroll
  for (int l = 0; l < 2; ++l) {
    const int idx = tid + l * 320;  // 0..639
    const int r = idx / 10;
    const int o = idx - r * 10;
    float acc = bs[o];
#pragma unroll
    for (int k = 0; k < 128; k += 4) {
      const float4 a = *reinterpret_cast<const float4*>(&Ss[r][k]);
      const float4 w = *reinterpret_cast<const float4*>(&Ws[o][k]);
      acc = fmaf(a.x, w.x, acc);
      acc = fmaf(a.y, w.y, acc);
      acc = fmaf(a.z, w.z, acc);
      acc = fmaf(a.w, w.w, acc);
    }
    C[(row0 + r) * 10 + o] = acc;
  }
}

// ---------------------------------------------------------------------------
// Output LIF scan: thread = (b,o), reads cur3[(b*T+t)*10+o],
// writes spikes to out[t*B*10 + b*10 + o]  (layout [T,B,O]).
// ---------------------------------------------------------------------------
__global__ __launch_bounds__(256) void lif_scan_out(
    const float* __restrict__ cur3, float* __restrict__ out) {
  const int g = blockIdx.x * 256 + threadIdx.x;  // 0..5119
  if (g >= kB * kO) return;
  const int b = g / kO;
  const int o = g - b * kO;
  float m = 0.0f, s = 0.0f;
#pragma unroll 4
  for (int t = 0; t < kT; ++t) {
    const float c = cur3[((size_t)b * kT + t) * kO + o];
    m = __fsub_rn(__fadd_rn(__fmul_rn(kBeta, m), c), s);
    s = (m > kThr) ? 1.0f : 0.0f;
    out[(size_t)t * (kB * kO) + g] = s;
  }
}

extern "C" void kernel_launch(void* const* d_in, const int* in_sizes, int n_in,
                              void* d_out, int out_size, void* d_ws,
                              size_t ws_size, hipStream_t stream) {
  (void)in_sizes;
  (void)n_in;
  (void)out_size;
  (void)ws_size;
  const float* x = (const float*)d_in[0];    // [B,T,784]
  const float* W1 = (const float*)d_in[1];   // [128,784]
  const float* b1 = (const float*)d_in[2];   // [128]
  const float* W2 = (const float*)d_in[3];   // [128,128]
  const float* b2 = (const float*)d_in[4];   // [128]
  const float* W3 = (const float*)d_in[5];   // [10,128]
  const float* b3 = (const float*)d_in[6];   // [10]
  float* out = (float*)d_out;                // [T,B,10]

  const size_t bufElems = (size_t)kM * kH;   // 13.1M floats = 52.4 MB
  float* P0 = (float*)d_ws;                  // partial0 -> s1 -> cur3
  float* P1 = P0 + bufElems;                 // partial1 -> cur2 -> s2

  // Layer 1: split-K GEMM (halves [0,400)/[400,784)), 1600 blocks.
  gemm8x16<kI, 1><<<2 * (kM / 128), 128, 0, stream>>>(x, W1, nullptr, P0,
                                                      bufElems);
  lif_scan13<<<(kB * kH) / 256, 256, 0, stream>>>(P0, P1, b1);
  // Layer 2: full-K GEMM, 800 blocks.
  gemm8x16<kH, 0><<<kM / 128, 128, 0, stream>>>(P0, W2, b2, P1, 0);
  lif_scan2<<<(kB * kH) / 256, 256, 0, stream>>>(P1);
  // Layer 3: cur3 -> P0 region (s1 dead).
  gemm3_n10<<<kM / 64, 320, 0, stream>>>(P1, W3, b3, P0);
  lif_scan_out<<<(kB * kO + 255) / 256, 256, 0, stream>>>(P0, out);
}

// Round 10
// 482.879 us; speedup vs baseline: 1.0312x; 1.0312x over previous
//
#include <hip/hip_runtime.h>

namespace {
constexpr int kB = 512;
constexpr int kT = 200;
constexpr int kI = 784;
constexpr int kH = 128;
constexpr int kO = 10;
constexpr int kM = kB * kT;  // 102400 rows
constexpr float kBeta = 0.9f;
constexpr float kThr = 1.0f;
constexpr int kSplitK0 = 400;  // 784 = 400 + 384, both % 16 == 0
}  // namespace

// ---------------------------------------------------------------------------
// Transpose W[N][K] row-major -> WT[K][N] row-major. 16x16 LDS tile.
// One-time cost (~5 us) so GEMM B-staging can use ds_write_b128.
// ---------------------------------------------------------------------------
__global__ __launch_bounds__(256) void transposeW(const float* __restrict__ W,
                                                  float* __restrict__ WT,
                                                  int N, int K) {
  __shared__ float t[16][17];
  const int k0 = blockIdx.x * 16, n0 = blockIdx.y * 16;
  const int tx = threadIdx.x & 15, ty = threadIdx.x >> 4;
  t[ty][tx] = W[(size_t)(n0 + ty) * K + k0 + tx];
  __syncthreads();
  WT[(size_t)(k0 + ty) * N + n0 + tx] = t[tx][ty];
}

// ---------------------------------------------------------------------------
// C[M][128] = A[M][K-slice] . BT[K-slice][128] (+ bias), BT = B^T (k-major).
// 128x128 tile, 128 threads (16 m-groups x 8 n-groups), 8x16 per-thread tile.
// r9 lesson: __launch_bounds__(128,2) made the allocator pin 128 VGPR and
// rematerialize LDS reads (VALUBusy 38%). Here: (128,1) -> ~160-VGPR budget
// (8 waves/CU bucket); inner loop keeps only b4[4] transient so live set is
// acc(128)+a(8)+b4(4)+addr ~= 150.
// LDS: As[16][132] (A-writes verified conflict-free, A-reads 2-way=free);
// Bs[16][160] with col swizzle n+((n>>4)<<2): B-reads start banks
// {0,20,8,28,16,4,24,12} -> conflict-free; B staged from pre-transposed WT
// with ds_write_b128 (4 instrs/thread/step vs 16 scalar).
// Per-output k-order unchanged from the passing r8 (ascending k per half).
// ---------------------------------------------------------------------------
template <int KSTRIDE, int SPLIT>
__global__ __launch_bounds__(128, 1) void gemm8x16(
    const float* __restrict__ A, const float* __restrict__ BT,
    const float* __restrict__ bias, float* __restrict__ C, size_t coff) {
  constexpr int BM = 128, BK = 16;
  __shared__ float As[BK][132];
  __shared__ float Bs[BK][160];
  const int tid = threadIdx.x;
  const int tn = tid & 7;    // n-group 0..7  (16 cols)
  const int tm = tid >> 3;   // m-group 0..15 (8 rows)
  int tile, kbeg, nsteps;
  if (SPLIT) {
    tile = blockIdx.x >> 1;
    const int half = blockIdx.x & 1;
    kbeg = half ? kSplitK0 : 0;
    nsteps = half ? (KSTRIDE - kSplitK0) / BK : kSplitK0 / BK;
    if (half) C += coff;
  } else {
    tile = blockIdx.x;
    kbeg = 0;
    nsteps = KSTRIDE / BK;
  }
  const int row0 = tile * BM;

  // A staging: 128 rows x 4 float4 = 512 / 128 thr = 4 each (transposed
  // scalar writes, conflict-free: banks (4(c4+j)+row)%32 all distinct).
  const int sar = tid >> 2;        // 0..31 (+32 per l)
  const int sac4 = (tid & 3) * 4;  // k offset 0,4,8,12
  // B staging from BT (k-major): idx = tid + l*128 -> kk = idx>>5,
  // n4 = (idx&31)*4; one b128 write per l.
  const int sbk = tid >> 5;        // 0..3 (+4 per l)
  const int sbn4 = (tid & 31) * 4; // 0..124

  const float* aptr = A + (size_t)(row0 + sar) * KSTRIDE + kbeg + sac4;
  const float* bptr = BT + (size_t)(kbeg + sbk) * 128 + sbn4;
  const int sbswz = sbn4 + ((sbn4 >> 4) << 2);  // swizzled B col

  float acc[8][16];
#pragma unroll
  for (int i = 0; i < 8; ++i)
#pragma unroll
    for (int j = 0; j < 16; ++j) acc[i][j] = 0.0f;

  for (int s = 0; s < nsteps; ++s) {
    const int k0 = s * BK;
    __syncthreads();
#pragma unroll
    for (int l = 0; l < 4; ++l) {
      const float4 va = *reinterpret_cast<const float4*>(
          aptr + (size_t)l * 32 * KSTRIDE + k0);
      const int r = sar + l * 32;
      As[sac4 + 0][r] = va.x; As[sac4 + 1][r] = va.y;
      As[sac4 + 2][r] = va.z; As[sac4 + 3][r] = va.w;
      const float4 vb = *reinterpret_cast<const float4*>(
          bptr + ((size_t)k0 + l * 4) * 128);
      *reinterpret_cast<float4*>(&Bs[sbk + l * 4][sbswz]) = vb;
    }
    __syncthreads();
#pragma unroll 2
    for (int kk = 0; kk < BK; ++kk) {
      float a[8];
      *reinterpret_cast<float4*>(&a[0]) =
          *reinterpret_cast<const float4*>(&As[kk][tm * 8]);
      *reinterpret_cast<float4*>(&a[4]) =
          *reinterpret_cast<const float4*>(&As[kk][tm * 8 + 4]);
#pragma unroll
      for (int q = 0; q < 4; ++q) {
        float b4[4];
        *reinterpret_cast<float4*>(&b4[0]) =
            *reinterpret_cast<const float4*>(&Bs[kk][tn * 20 + q * 4]);
#pragma unroll
        for (int i = 0; i < 8; ++i) {
          acc[i][q * 4 + 0] = fmaf(a[i], b4[0], acc[i][q * 4 + 0]);
          acc[i][q * 4 + 1] = fmaf(a[i], b4[1], acc[i][q * 4 + 1]);
          acc[i][q * 4 + 2] = fmaf(a[i], b4[2], acc[i][q * 4 + 2]);
          acc[i][q * 4 + 3] = fmaf(a[i], b4[3], acc[i][q * 4 + 3]);
        }
      }
    }
  }

#pragma unroll
  for (int i = 0; i < 8; ++i) {
    const size_t r = (size_t)(row0 + tm * 8 + i);
#pragma unroll
    for (int q = 0; q < 4; ++q) {
      const int n = tn * 16 + q * 4;
      float4 v;
      v.x = acc[i][q * 4 + 0];
      v.y = acc[i][q * 4 + 1];
      v.z = acc[i][q * 4 + 2];
      v.w = acc[i][q * 4 + 3];
      if (bias != nullptr) {
        v.x += bias[n + 0];
        v.y += bias[n + 1];
        v.z += bias[n + 2];
        v.w += bias[n + 3];
      }
      *reinterpret_cast<float4*>(&C[r * 128 + n]) = v;
    }
  }
}

// ---------------------------------------------------------------------------
// Layer-1 LIF scan + partial combine: cur = (P0+P1) + b1; spikes -> P0.
// _rn op order matches numpy exactly; combine order proven in r7/r8.
// ---------------------------------------------------------------------------
__global__ __launch_bounds__(256) void lif_scan13(
    float* __restrict__ P0, const float* __restrict__ P1,
    const float* __restrict__ b1) {
  const int g = blockIdx.x * 256 + threadIdx.x;  // 0..65535
  const int b = g >> 7;
  const int h = g & 127;
  const size_t base = (size_t)b * kT * 128 + h;
  const float bb = b1[h];
  float m = 0.0f, s = 0.0f;
#pragma unroll 4
  for (int t = 0; t < kT; ++t) {
    const size_t idx = base + (size_t)t * 128;
    const float cur = __fadd_rn(__fadd_rn(P0[idx], P1[idx]), bb);
    m = __fsub_rn(__fadd_rn(__fmul_rn(kBeta, m), cur), s);
    s = (m > kThr) ? 1.0f : 0.0f;
    P0[idx] = s;
  }
}

// ---------------------------------------------------------------------------
// Layer-2 LIF scan, in place (bias already applied by GEMM2).
// ---------------------------------------------------------------------------
__global__ __launch_bounds__(256) void lif_scan2(float* __restrict__ buf) {
  const int g = blockIdx.x * 256 + threadIdx.x;  // 0..65535
  const int b = g >> 7;
  const int h = g & 127;
  const size_t base = (size_t)b * kT * 128 + h;
  float m = 0.0f, s = 0.0f;
#pragma unroll 4
  for (int t = 0; t < kT; ++t) {
    const size_t idx = base + (size_t)t * 128;
    m = __fsub_rn(__fadd_rn(__fmul_rn(kBeta, m), buf[idx]), s);
    s = (m > kThr) ? 1.0f : 0.0f;
    buf[idx] = s;
  }
}

// ---------------------------------------------------------------------------
// GEMM3: cur3[M][10] = s2[M][128] . W3[10][128]^T + b3. 64 rows / block,
// 320 threads, A-tile + W3 staged in LDS, 2 outputs per thread.
// ---------------------------------------------------------------------------
__global__ __launch_bounds__(320) void gemm3_n10(
    const float* __restrict__ A, const float* __restrict__ W3,
    const float* __restrict__ b3, float* __restrict__ C) {
  __shared__ float Ss[64][132];
  __shared__ float Ws[10][132];
  __shared__ float bs[10];
  const int tid = threadIdx.x;
  const size_t row0 = (size_t)blockIdx.x * 64;

  {  // stage W3: 10*128 floats = 320 float4, exactly one per thread
    const int r = tid >> 5;
    const int c4 = (tid & 31) * 4;
    const float4 v = *reinterpret_cast<const float4*>(&W3[r * 128 + c4]);
    Ws[r][c4 + 0] = v.x;
    Ws[r][c4 + 1] = v.y;
    Ws[r][c4 + 2] = v.z;
    Ws[r][c4 + 3] = v.w;
    if (tid < 10) bs[tid] = b3[tid];
  }
  for (int fi = tid; fi < 2048; fi += 320) {  // 64 rows * 32 float4
    const int r = fi >> 5;
    const int c4 = (fi & 31) * 4;
    const float4 v =
        *reinterpret_cast<const float4*>(&A[(row0 + r) * 128 + c4]);
    Ss[r][c4 + 0] = v.x;
    Ss[r][c4 + 1] = v.y;
    Ss[r][c4 + 2] = v.z;
    Ss[r][c4 + 3] = v.w;
  }
  __syncthreads();

#pragma unroll
  for (int l = 0; l < 2; ++l) {
    const int idx = tid + l * 320;  // 0..639
    const int r = idx / 10;
    const int o = idx - r * 10;
    float acc = bs[o];
#pragma unroll
    for (int k = 0; k < 128; k += 4) {
      const float4 a = *reinterpret_cast<const float4*>(&Ss[r][k]);
      const float4 w = *reinterpret_cast<const float4*>(&Ws[o][k]);
      acc = fmaf(a.x, w.x, acc);
      acc = fmaf(a.y, w.y, acc);
      acc = fmaf(a.z, w.z, acc);
      acc = fmaf(a.w, w.w, acc);
    }
    C[(row0 + r) * 10 + o] = acc;
  }
}

// ---------------------------------------------------------------------------
// Output LIF scan: thread = (b,o), reads cur3[(b*T+t)*10+o],
// writes spikes to out[t*B*10 + b*10 + o]  (layout [T,B,O]).
// ---------------------------------------------------------------------------
__global__ __launch_bounds__(256) void lif_scan_out(
    const float* __restrict__ cur3, float* __restrict__ out) {
  const int g = blockIdx.x * 256 + threadIdx.x;  // 0..5119
  if (g >= kB * kO) return;
  const int b = g / kO;
  const int o = g - b * kO;
  float m = 0.0f, s = 0.0f;
#pragma unroll 4
  for (int t = 0; t < kT; ++t) {
    const float c = cur3[((size_t)b * kT + t) * kO + o];
    m = __fsub_rn(__fadd_rn(__fmul_rn(kBeta, m), c), s);
    s = (m > kThr) ? 1.0f : 0.0f;
    out[(size_t)t * (kB * kO) + g] = s;
  }
}

extern "C" void kernel_launch(void* const* d_in, const int* in_sizes, int n_in,
                              void* d_out, int out_size, void* d_ws,
                              size_t ws_size, hipStream_t stream) {
  (void)in_sizes;
  (void)n_in;
  (void)out_size;
  const float* x = (const float*)d_in[0];    // [B,T,784]
  const float* W1 = (const float*)d_in[1];   // [128,784]
  const float* b1 = (const float*)d_in[2];   // [128]
  const float* W2 = (const float*)d_in[3];   // [128,128]
  const float* b2 = (const float*)d_in[4];   // [128]
  const float* W3 = (const float*)d_in[5];   // [10,128]
  const float* b3 = (const float*)d_in[6];   // [10]
  float* out = (float*)d_out;                // [T,B,10]

  const size_t bufElems = (size_t)kM * kH;   // 13.1M floats = 52.4 MB
  float* P0 = (float*)d_ws;                  // partial0 -> s1 -> cur3
  float* P1 = P0 + bufElems;                 // partial1 -> cur2 -> s2

  // W1T (784x128) + W2T (128x128): 467 KB. Prefer d_ws tail if it fits,
  // else stash in d_out (fully overwritten by lif_scan_out at the end;
  // ws_size is constant per session so the branch is deterministic).
  const size_t wtElems = (size_t)kI * kH + (size_t)kH * kH;
  float* W1T;
  if (ws_size >= (2 * bufElems + wtElems) * sizeof(float)) {
    W1T = P1 + bufElems;
  } else {
    W1T = out;  // 467KB << 4.1MB out buffer
  }
  float* W2T = W1T + (size_t)kI * kH;

  transposeW<<<dim3(kI / 16, kH / 16), 256, 0, stream>>>(W1, W1T, kH, kI);
  transposeW<<<dim3(kH / 16, kH / 16), 256, 0, stream>>>(W2, W2T, kH, kH);

  // Layer 1: split-K GEMM (halves [0,400)/[400,784)), 1600 blocks.
  gemm8x16<kI, 1><<<2 * (kM / 128), 128, 0, stream>>>(x, W1T, nullptr, P0,
                                                      bufElems);
  lif_scan13<<<(kB * kH) / 256, 256, 0, stream>>>(P0, P1, b1);
  // Layer 2: full-K GEMM, 800 blocks.
  gemm8x16<kH, 0><<<kM / 128, 128, 0, stream>>>(P0, W2T, b2, P1, 0);
  lif_scan2<<<(kB * kH) / 256, 256, 0, stream>>>(P1);
  // Layer 3: cur3 -> P0 region (s1 dead).
  gemm3_n10<<<kM / 64, 320, 0, stream>>>(P1, W3, b3, P0);
  lif_scan_out<<<(kB * kO + 255) / 256, 256, 0, stream>>>(P0, out);
}

// Round 11
// 407.785 us; speedup vs baseline: 1.2211x; 1.1842x over previous
//
#include <hip/hip_runtime.h>

namespace {
constexpr int kB = 512;
constexpr int kT = 200;
constexpr int kI = 784;
constexpr int kH = 128;
constexpr int kO = 10;
constexpr int kM = kB * kT;  // 102400 rows
constexpr float kBeta = 0.9f;
constexpr float kThr = 1.0f;
constexpr int kSplitK0 = 400;  // 784 = 400 + 384, both % 16 == 0
}  // namespace

// ---------------------------------------------------------------------------
// Helpers for the pipelined 64x128 GEMM. Static distinct LDS arrays passed
// by reference (r6-proven allocation-clean style; runtime-indexed buffers
// and lambdas trigger hipcc's scratch pathology — r2-r5).
// ---------------------------------------------------------------------------
__device__ __forceinline__ void gload64(float4 (&ra)[2], float4 (&rb)[4],
                                        const float* __restrict__ aptr,
                                        const float* __restrict__ bptr,
                                        int KS, int k0) {
  ra[0] = *reinterpret_cast<const float4*>(aptr + k0);
  ra[1] = *reinterpret_cast<const float4*>(aptr + (size_t)32 * KS + k0);
#pragma unroll
  for (int l = 0; l < 4; ++l)
    rb[l] = *reinterpret_cast<const float4*>(bptr + (size_t)l * 32 * KS + k0);
}

__device__ __forceinline__ void ldswrite64(float (&As)[16][68],
                                           float (&Bs)[16][132],
                                           const float4 (&ra)[2],
                                           const float4 (&rb)[4], int ar0,
                                           int ac4, int br, int bc4) {
  As[ac4 + 0][ar0] = ra[0].x; As[ac4 + 1][ar0] = ra[0].y;
  As[ac4 + 2][ar0] = ra[0].z; As[ac4 + 3][ar0] = ra[0].w;
  As[ac4 + 0][ar0 + 32] = ra[1].x; As[ac4 + 1][ar0 + 32] = ra[1].y;
  As[ac4 + 2][ar0 + 32] = ra[1].z; As[ac4 + 3][ar0 + 32] = ra[1].w;
#pragma unroll
  for (int l = 0; l < 4; ++l) {
    const int r = br + l * 32;
    Bs[bc4 + 0][r] = rb[l].x; Bs[bc4 + 1][r] = rb[l].y;
    Bs[bc4 + 2][r] = rb[l].z; Bs[bc4 + 3][r] = rb[l].w;
  }
}

__device__ __forceinline__ void fma64(const float (&As)[16][68],
                                      const float (&Bs)[16][132], int ty4,
                                      int tx4, float (&acc)[8][8]) {
#pragma unroll
  for (int kk = 0; kk < 16; ++kk) {
    float a[8], b[8];
    *reinterpret_cast<float4*>(&a[0]) =
        *reinterpret_cast<const float4*>(&As[kk][ty4]);
    *reinterpret_cast<float4*>(&a[4]) =
        *reinterpret_cast<const float4*>(&As[kk][32 + ty4]);
    *reinterpret_cast<float4*>(&b[0]) =
        *reinterpret_cast<const float4*>(&Bs[kk][tx4]);
    *reinterpret_cast<float4*>(&b[4]) =
        *reinterpret_cast<const float4*>(&Bs[kk][64 + tx4]);
#pragma unroll
    for (int i = 0; i < 8; ++i)
#pragma unroll
      for (int j = 0; j < 8; ++j) acc[i][j] = fmaf(a[i], b[j], acc[i][j]);
  }
}

// ---------------------------------------------------------------------------
// C[M][128] = A[M][K-slice] . B[128][K-slice]^T (+ bias).
// r8's proven 64x128 / 128-thread / 8x8-tile shape + double-buffered LDS
// pipeline: loads for tile s+1 are issued BEFORE compute(s) (in flight
// across ~2048cy of FMA), ds_writes go to the idle buffer, ONE barrier per
// step. r6 proved this static-buffer style allocates cleanly; r6's mistake
// (loads issued after compute -> exposed latency) is fixed here.
// Per-output k-order unchanged (ascending k per half) -> bitwise-identical.
// ---------------------------------------------------------------------------
template <int KSTRIDE, int SPLIT>
__global__ __launch_bounds__(128, 2) void gemm64p(
    const float* __restrict__ A, const float* __restrict__ B,
    const float* __restrict__ bias, float* __restrict__ C, size_t coff) {
  constexpr int BM = 64, BK = 16;
  __shared__ float As0[16][68];
  __shared__ float Bs0[16][132];
  __shared__ float As1[16][68];
  __shared__ float Bs1[16][132];
  const int tid = threadIdx.x;
  const int tx4 = (tid & 15) * 4;  // n
  const int ty4 = (tid >> 4) * 4;  // m (0..28)
  int tile, kbeg, nsteps;
  if (SPLIT) {
    tile = blockIdx.x >> 1;
    const int half = blockIdx.x & 1;
    kbeg = half ? kSplitK0 : 0;
    nsteps = half ? (KSTRIDE - kSplitK0) / BK : kSplitK0 / BK;
    if (half) C += coff;
  } else {
    tile = blockIdx.x;
    kbeg = 0;
    nsteps = KSTRIDE / BK;
  }
  const int row0 = tile * BM;
  const int kLast = (nsteps - 1) * BK;  // clamp target for prefetch

  const int ar0 = tid >> 2;        // 0..31
  const int ac4 = (tid & 3) * 4;
  const int br = tid >> 2;         // 0..31
  const int bc4 = (tid & 3) * 4;

  const float* aptr = A + (size_t)(row0 + ar0) * KSTRIDE + kbeg + ac4;
  const float* bptr = B + (size_t)br * KSTRIDE + kbeg + bc4;

  float acc[8][8];
#pragma unroll
  for (int i = 0; i < 8; ++i)
#pragma unroll
    for (int j = 0; j < 8; ++j) acc[i][j] = 0.0f;

  float4 ra[2], rb[4];
  // prologue: tile 0 -> buf0 ; tile 1 -> regs (clamped if nsteps==1)
  gload64(ra, rb, aptr, bptr, KSTRIDE, 0);
  ldswrite64(As0, Bs0, ra, rb, ar0, ac4, br, bc4);
  gload64(ra, rb, aptr, bptr, KSTRIDE, (BK <= kLast) ? BK : kLast);
  __syncthreads();

  int s = 0;
  while (true) {
    // regs hold tile s+1 (in flight since before previous barrier)
    fma64(As0, Bs0, ty4, tx4, acc);
    if (s + 1 >= nsteps) break;
    ldswrite64(As1, Bs1, ra, rb, ar0, ac4, br, bc4);
    {
      const int kn = ((s + 2) * BK <= kLast) ? (s + 2) * BK : kLast;
      gload64(ra, rb, aptr, bptr, KSTRIDE, kn);
    }
    __syncthreads();
    fma64(As1, Bs1, ty4, tx4, acc);
    if (s + 2 >= nsteps) break;
    ldswrite64(As0, Bs0, ra, rb, ar0, ac4, br, bc4);
    {
      const int kn = ((s + 3) * BK <= kLast) ? (s + 3) * BK : kLast;
      gload64(ra, rb, aptr, bptr, KSTRIDE, kn);
    }
    __syncthreads();
    s += 2;
  }

#pragma unroll
  for (int i = 0; i < 8; ++i) {
    const int m = (i < 4) ? (ty4 + i) : (32 + ty4 + (i - 4));
    const size_t r = (size_t)(row0 + m);
#pragma unroll
    for (int jh = 0; jh < 2; ++jh) {
      const int n = jh * 64 + tx4;
      float4 v;
      v.x = acc[i][jh * 4 + 0];
      v.y = acc[i][jh * 4 + 1];
      v.z = acc[i][jh * 4 + 2];
      v.w = acc[i][jh * 4 + 3];
      if (bias != nullptr) {
        v.x += bias[n + 0];
        v.y += bias[n + 1];
        v.z += bias[n + 2];
        v.w += bias[n + 3];
      }
      *reinterpret_cast<float4*>(&C[r * 128 + n]) = v;
    }
  }
}

// ---------------------------------------------------------------------------
// Layer-1 LIF scan + partial combine: cur = (P0+P1) + b1; spikes -> P0.
// _rn op order matches numpy exactly; combine order proven in r7/r8.
// ---------------------------------------------------------------------------
__global__ __launch_bounds__(256) void lif_scan13(
    float* __restrict__ P0, const float* __restrict__ P1,
    const float* __restrict__ b1) {
  const int g = blockIdx.x * 256 + threadIdx.x;  // 0..65535
  const int b = g >> 7;
  const int h = g & 127;
  const size_t base = (size_t)b * kT * 128 + h;
  const float bb = b1[h];
  float m = 0.0f, s = 0.0f;
#pragma unroll 4
  for (int t = 0; t < kT; ++t) {
    const size_t idx = base + (size_t)t * 128;
    const float cur = __fadd_rn(__fadd_rn(P0[idx], P1[idx]), bb);
    m = __fsub_rn(__fadd_rn(__fmul_rn(kBeta, m), cur), s);
    s = (m > kThr) ? 1.0f : 0.0f;
    P0[idx] = s;
  }
}

// ---------------------------------------------------------------------------
// Layer-2 LIF scan, in place (bias already applied by GEMM2).
// ---------------------------------------------------------------------------
__global__ __launch_bounds__(256) void lif_scan2(float* __restrict__ buf) {
  const int g = blockIdx.x * 256 + threadIdx.x;  // 0..65535
  const int b = g >> 7;
  const int h = g & 127;
  const size_t base = (size_t)b * kT * 128 + h;
  float m = 0.0f, s = 0.0f;
#pragma unroll 4
  for (int t = 0; t < kT; ++t) {
    const size_t idx = base + (size_t)t * 128;
    m = __fsub_rn(__fadd_rn(__fmul_rn(kBeta, m), buf[idx]), s);
    s = (m > kThr) ? 1.0f : 0.0f;
    buf[idx] = s;
  }
}

// ---------------------------------------------------------------------------
// GEMM3: cur3[M][10] = s2[M][128] . W3[10][128]^T + b3. 64 rows / block,
// 320 threads, A-tile + W3 staged in LDS, 2 outputs per thread.
// ---------------------------------------------------------------------------
__global__ __launch_bounds__(320) void gemm3_n10(
    const float* __restrict__ A, const float* __restrict__ W3,
    const float* __restrict__ b3, float* __restrict__ C) {
  __shared__ float Ss[64][132];
  __shared__ float Ws[10][132];
  __shared__ float bs[10];
  const int tid = threadIdx.x;
  const size_t row0 = (size_t)blockIdx.x * 64;

  {  // stage W3: 10*128 floats = 320 float4, exactly one per thread
    const int r = tid >> 5;
    const int c4 = (tid & 31) * 4;
    const float4 v = *reinterpret_cast<const float4*>(&W3[r * 128 + c4]);
    Ws[r][c4 + 0] = v.x;
    Ws[r][c4 + 1] = v.y;
    Ws[r][c4 + 2] = v.z;
    Ws[r][c4 + 3] = v.w;
    if (tid < 10) bs[tid] = b3[tid];
  }
  for (int fi = tid; fi < 2048; fi += 320) {  // 64 rows * 32 float4
    const int r = fi >> 5;
    const int c4 = (fi & 31) * 4;
    const float4 v =
        *reinterpret_cast<const float4*>(&A[(row0 + r) * 128 + c4]);
    Ss[r][c4 + 0] = v.x;
    Ss[r][c4 + 1] = v.y;
    Ss[r][c4 + 2] = v.z;
    Ss[r][c4 + 3] = v.w;
  }
  __syncthreads();

#pragma unroll
  for (int l = 0; l < 2; ++l) {
    const int idx = tid + l * 320;  // 0..639
    const int r = idx / 10;
    const int o = idx - r * 10;
    float acc = bs[o];
#pragma unroll
    for (int k = 0; k < 128; k += 4) {
      const float4 a = *reinterpret_cast<const float4*>(&Ss[r][k]);
      const float4 w = *reinterpret_cast<const float4*>(&Ws[o][k]);
      acc = fmaf(a.x, w.x, acc);
      acc = fmaf(a.y, w.y, acc);
      acc = fmaf(a.z, w.z, acc);
      acc = fmaf(a.w, w.w, acc);
    }
    C[(row0 + r) * 10 + o] = acc;
  }
}

// ---------------------------------------------------------------------------
// Output LIF scan: thread = (b,o), reads cur3[(b*T+t)*10+o],
// writes spikes to out[t*B*10 + b*10 + o]  (layout [T,B,O]).
// ---------------------------------------------------------------------------
__global__ __launch_bounds__(256) void lif_scan_out(
    const float* __restrict__ cur3, float* __restrict__ out) {
  const int g = blockIdx.x * 256 + threadIdx.x;  // 0..5119
  if (g >= kB * kO) return;
  const int b = g / kO;
  const int o = g - b * kO;
  float m = 0.0f, s = 0.0f;
#pragma unroll 4
  for (int t = 0; t < kT; ++t) {
    const float c = cur3[((size_t)b * kT + t) * kO + o];
    m = __fsub_rn(__fadd_rn(__fmul_rn(kBeta, m), c), s);
    s = (m > kThr) ? 1.0f : 0.0f;
    out[(size_t)t * (kB * kO) + g] = s;
  }
}

extern "C" void kernel_launch(void* const* d_in, const int* in_sizes, int n_in,
                              void* d_out, int out_size, void* d_ws,
                              size_t ws_size, hipStream_t stream) {
  (void)in_sizes;
  (void)n_in;
  (void)out_size;
  (void)ws_size;
  const float* x = (const float*)d_in[0];    // [B,T,784]
  const float* W1 = (const float*)d_in[1];   // [128,784]
  const float* b1 = (const float*)d_in[2];   // [128]
  const float* W2 = (const float*)d_in[3];   // [128,128]
  const float* b2 = (const float*)d_in[4];   // [128]
  const float* W3 = (const float*)d_in[5];   // [10,128]
  const float* b3 = (const float*)d_in[6];   // [10]
  float* out = (float*)d_out;                // [T,B,10]

  const size_t bufElems = (size_t)kM * kH;   // 13.1M floats = 52.4 MB
  float* P0 = (float*)d_ws;                  // partial0 -> s1 -> cur3
  float* P1 = P0 + bufElems;                 // partial1 -> cur2 -> s2

  // Layer 1: split-K GEMM, 3200 blocks x 128 threads; scan combines.
  gemm64p<kI, 1><<<2 * (kM / 64), 128, 0, stream>>>(x, W1, nullptr, P0,
                                                    bufElems);
  lif_scan13<<<(kB * kH) / 256, 256, 0, stream>>>(P0, P1, b1);
  // Layer 2: full-K GEMM, 1600 blocks.
  gemm64p<kH, 0><<<kM / 64, 128, 0, stream>>>(P0, W2, b2, P1, 0);
  lif_scan2<<<(kB * kH) / 256, 256, 0, stream>>>(P1);
  // Layer 3: cur3 -> P0 region (s1 dead).
  gemm3_n10<<<kM / 64, 320, 0, stream>>>(P1, W3, b3, P0);
  lif_scan_out<<<(kB * kO + 255) / 256, 256, 0, stream>>>(P0, out);
}

// Round 12
// 401.113 us; speedup vs baseline: 1.2414x; 1.0166x over previous
//
#include <hip/hip_runtime.h>

namespace {
constexpr int kB = 512;
constexpr int kT = 200;
constexpr int kI = 784;
constexpr int kH = 128;
constexpr int kO = 10;
constexpr int kM = kB * kT;  // 102400 rows
constexpr float kBeta = 0.9f;
constexpr float kThr = 1.0f;
constexpr int kSplitK0 = 400;  // 784 = 400 + 384, both % 16 == 0
}  // namespace

// ---------------------------------------------------------------------------
// Transpose W[N][K] -> WT[K][N]. 16x16 LDS tile. Proven in r10 (absmax 0.0).
// ---------------------------------------------------------------------------
__global__ __launch_bounds__(256) void transposeW(const float* __restrict__ W,
                                                  float* __restrict__ WT,
                                                  int N, int K) {
  __shared__ float t[16][17];
  const int k0 = blockIdx.x * 16, n0 = blockIdx.y * 16;
  const int tx = threadIdx.x & 15, ty = threadIdx.x >> 4;
  t[ty][tx] = W[(size_t)(n0 + ty) * K + k0 + tx];
  __syncthreads();
  WT[(size_t)(k0 + ty) * N + n0 + tx] = t[tx][ty];
}

// ---------------------------------------------------------------------------
// C[M][128] = A[M][K-slice] . BT[K-slice][128] (+ bias); BT = W^T (k-major).
// r8's proven 64x128 / 128-thread / 8x8-tile shape (276us, VGPR 64, clean),
// ONE change: B staged from pre-transposed BT with 4 coalesced b128 loads +
// 4 ds_write_b128 (was 4 strided loads + 16 scalar writes). LDS contents and
// every read/FMA/store identical to r8 -> bitwise-identical output.
// ---------------------------------------------------------------------------
template <int KSTRIDE, int SPLIT>
__global__ __launch_bounds__(128, 4) void gemm64bt(
    const float* __restrict__ A, const float* __restrict__ BT,
    const float* __restrict__ bias, float* __restrict__ C, size_t coff) {
  constexpr int BM = 64, BK = 16;
  __shared__ float As[BK][68];
  __shared__ float Bs[BK][132];
  const int tid = threadIdx.x;
  const int tx = tid & 15;   // n-dim 0..15
  const int ty = tid >> 4;   // m-dim 0..7
  int tile, kbeg, nsteps;
  if (SPLIT) {
    tile = blockIdx.x >> 1;
    const int half = blockIdx.x & 1;
    kbeg = half ? kSplitK0 : 0;
    nsteps = half ? (KSTRIDE - kSplitK0) / BK : kSplitK0 / BK;
    if (half) C += coff;
  } else {
    tile = blockIdx.x;
    kbeg = 0;
    nsteps = KSTRIDE / BK;
  }
  const int row0 = tile * BM;

  // A staging (as r8): 64 rows x 16 k, thread -> 2 rows, 4 k each.
  const int ar0 = tid >> 2;        // 0..31
  const int ar1 = ar0 + 32;
  const int ac4 = (tid & 3) * 4;
  // B staging from BT: 16 rows(k) x 128 n = 512 float4; thread ->
  // (sbk + l*4, sbn4) for l=0..3; coalesced 512B per row-instr.
  const int sbk = tid >> 5;        // 0..3
  const int sbn4 = (tid & 31) * 4; // 0..124

  const float* aptr = A + (size_t)(row0 + ar0) * KSTRIDE + kbeg + ac4;
  const float* btptr = BT + (size_t)(kbeg + sbk) * 128 + sbn4;

  float acc[8][8];
#pragma unroll
  for (int i = 0; i < 8; ++i)
#pragma unroll
    for (int j = 0; j < 8; ++j) acc[i][j] = 0.0f;

  for (int s = 0; s < nsteps; ++s) {
    const int k0 = s * BK;
    __syncthreads();
    {
      const float4 va0 = *reinterpret_cast<const float4*>(aptr + k0);
      const float4 va1 = *reinterpret_cast<const float4*>(
          aptr + (size_t)32 * KSTRIDE + k0);
      As[ac4 + 0][ar0] = va0.x; As[ac4 + 1][ar0] = va0.y;
      As[ac4 + 2][ar0] = va0.z; As[ac4 + 3][ar0] = va0.w;
      As[ac4 + 0][ar1] = va1.x; As[ac4 + 1][ar1] = va1.y;
      As[ac4 + 2][ar1] = va1.z; As[ac4 + 3][ar1] = va1.w;
#pragma unroll
      for (int l = 0; l < 4; ++l) {
        const float4 vb = *reinterpret_cast<const float4*>(
            btptr + (size_t)(k0 + l * 4) * 128);
        *reinterpret_cast<float4*>(&Bs[sbk + l * 4][sbn4]) = vb;
      }
    }
    __syncthreads();
#pragma unroll
    for (int kk = 0; kk < BK; ++kk) {
      float a[8], b[8];
      *reinterpret_cast<float4*>(&a[0]) =
          *reinterpret_cast<const float4*>(&As[kk][ty * 4]);
      *reinterpret_cast<float4*>(&a[4]) =
          *reinterpret_cast<const float4*>(&As[kk][32 + ty * 4]);
      *reinterpret_cast<float4*>(&b[0]) =
          *reinterpret_cast<const float4*>(&Bs[kk][tx * 4]);
      *reinterpret_cast<float4*>(&b[4]) =
          *reinterpret_cast<const float4*>(&Bs[kk][64 + tx * 4]);
#pragma unroll
      for (int i = 0; i < 8; ++i)
#pragma unroll
        for (int j = 0; j < 8; ++j) acc[i][j] = fmaf(a[i], b[j], acc[i][j]);
    }
  }

#pragma unroll
  for (int i = 0; i < 8; ++i) {
    const int m = (i < 4) ? (ty * 4 + i) : (32 + ty * 4 + (i - 4));
    const size_t r = (size_t)(row0 + m);
#pragma unroll
    for (int jh = 0; jh < 2; ++jh) {
      const int n = jh * 64 + tx * 4;
      float4 v;
      v.x = acc[i][jh * 4 + 0];
      v.y = acc[i][jh * 4 + 1];
      v.z = acc[i][jh * 4 + 2];
      v.w = acc[i][jh * 4 + 3];
      if (bias != nullptr) {
        v.x += bias[n + 0];
        v.y += bias[n + 1];
        v.z += bias[n + 2];
        v.w += bias[n + 3];
      }
      *reinterpret_cast<float4*>(&C[r * 128 + n]) = v;
    }
  }
}

#define LIF_STEP(mm, ss, curexpr)                                      \
  {                                                                    \
    const float cur_ = (curexpr);                                      \
    mm = __fsub_rn(__fadd_rn(__fmul_rn(kBeta, mm), cur_), ss);         \
    ss = (mm > kThr) ? 1.0f : 0.0f;                                    \
  }

// ---------------------------------------------------------------------------
// Layer-1 LIF scan + combine: cur = (P0+P1)+b1; spikes -> P0.
// 32768 threads (256 blk x 128), thread = (b, h-pair), float2 chains,
// explicit depth-4 load pipeline: ~8KB in flight per CU -> HBM-BW-bound
// (r8's scalar version was latency-bound at ~2KB/CU in flight).
// Per-element op order identical to the passing r7/r8 version.
// ---------------------------------------------------------------------------
__global__ __launch_bounds__(128) void lif_scan13(
    float* __restrict__ P0, const float* __restrict__ P1,
    const float* __restrict__ b1) {
  const int g = blockIdx.x * 128 + threadIdx.x;  // 0..32767
  const int b = g >> 6;
  const int h2 = (g & 63) * 2;
  const size_t base = (size_t)b * kT * 128 + h2;
  const float bb0 = b1[h2], bb1 = b1[h2 + 1];
#define LD0(t) (*reinterpret_cast<const float2*>(&P0[base + (size_t)(t)*128]))
#define LD1(t) (*reinterpret_cast<const float2*>(&P1[base + (size_t)(t)*128]))
  float2 cA0 = LD0(0), cA1 = LD1(0), cB0 = LD0(1), cB1 = LD1(1);
  float2 cC0 = LD0(2), cC1 = LD1(2), cD0 = LD0(3), cD1 = LD1(3);
  float m0 = 0.f, m1 = 0.f, s0 = 0.f, s1 = 0.f;
  for (int t = 0; t < kT; t += 2) {
    const int pa = (t + 4 < kT) ? t + 4 : kT - 1;
    const int pb = (t + 5 < kT) ? t + 5 : kT - 1;
    const float2 nA0 = LD0(pa), nA1 = LD1(pa);
    const float2 nB0 = LD0(pb), nB1 = LD1(pb);
    LIF_STEP(m0, s0, __fadd_rn(__fadd_rn(cA0.x, cA1.x), bb0));
    LIF_STEP(m1, s1, __fadd_rn(__fadd_rn(cA0.y, cA1.y), bb1));
    *reinterpret_cast<float2*>(&P0[base + (size_t)t * 128]) =
        make_float2(s0, s1);
    LIF_STEP(m0, s0, __fadd_rn(__fadd_rn(cB0.x, cB1.x), bb0));
    LIF_STEP(m1, s1, __fadd_rn(__fadd_rn(cB0.y, cB1.y), bb1));
    *reinterpret_cast<float2*>(&P0[base + (size_t)(t + 1) * 128]) =
        make_float2(s0, s1);
    cA0 = cC0; cA1 = cC1; cB0 = cD0; cB1 = cD1;
    cC0 = nA0; cC1 = nA1; cD0 = nB0; cD1 = nB1;
  }
#undef LD0
#undef LD1
}

// ---------------------------------------------------------------------------
// Layer-2 LIF scan, in place (bias applied by GEMM2). Same pipeline scheme.
// ---------------------------------------------------------------------------
__global__ __launch_bounds__(128) void lif_scan2(float* __restrict__ buf) {
  const int g = blockIdx.x * 128 + threadIdx.x;  // 0..32767
  const int b = g >> 6;
  const int h2 = (g & 63) * 2;
  const size_t base = (size_t)b * kT * 128 + h2;
#define LD(t) (*reinterpret_cast<const float2*>(&buf[base + (size_t)(t)*128]))
  float2 cA = LD(0), cB = LD(1), cC = LD(2), cD = LD(3);
  float m0 = 0.f, m1 = 0.f, s0 = 0.f, s1 = 0.f;
  for (int t = 0; t < kT; t += 2) {
    const int pa = (t + 4 < kT) ? t + 4 : kT - 1;
    const int pb = (t + 5 < kT) ? t + 5 : kT - 1;
    const float2 nA = LD(pa), nB = LD(pb);
    LIF_STEP(m0, s0, cA.x);
    LIF_STEP(m1, s1, cA.y);
    *reinterpret_cast<float2*>(&buf[base + (size_t)t * 128]) =
        make_float2(s0, s1);
    LIF_STEP(m0, s0, cB.x);
    LIF_STEP(m1, s1, cB.y);
    *reinterpret_cast<float2*>(&buf[base + (size_t)(t + 1) * 128]) =
        make_float2(s0, s1);
    cA = cC; cB = cD; cC = nA; cD = nB;
  }
#undef LD
}

// ---------------------------------------------------------------------------
// GEMM3: cur3[M][10] = s2[M][128] . W3[10][128]^T + b3. (r8's, unchanged)
// ---------------------------------------------------------------------------
__global__ __launch_bounds__(320) void gemm3_n10(
    const float* __restrict__ A, const float* __restrict__ W3,
    const float* __restrict__ b3, float* __restrict__ C) {
  __shared__ float Ss[64][132];
  __shared__ float Ws[10][132];
  __shared__ float bs[10];
  const int tid = threadIdx.x;
  const size_t row0 = (size_t)blockIdx.x * 64;

  {
    const int r = tid >> 5;
    const int c4 = (tid & 31) * 4;
    const float4 v = *reinterpret_cast<const float4*>(&W3[r * 128 + c4]);
    Ws[r][c4 + 0] = v.x;
    Ws[r][c4 + 1] = v.y;
    Ws[r][c4 + 2] = v.z;
    Ws[r][c4 + 3] = v.w;
    if (tid < 10) bs[tid] = b3[tid];
  }
  for (int fi = tid; fi < 2048; fi += 320) {
    const int r = fi >> 5;
    const int c4 = (fi & 31) * 4;
    const float4 v =
        *reinterpret_cast<const float4*>(&A[(row0 + r) * 128 + c4]);
    Ss[r][c4 + 0] = v.x;
    Ss[r][c4 + 1] = v.y;
    Ss[r][c4 + 2] = v.z;
    Ss[r][c4 + 3] = v.w;
  }
  __syncthreads();

#pragma unroll
  for (int l = 0; l < 2; ++l) {
    const int idx = tid + l * 320;
    const int r = idx / 10;
    const int o = idx - r * 10;
    float acc = bs[o];
#pragma unroll
    for (int k = 0; k < 128; k += 4) {
      const float4 a = *reinterpret_cast<const float4*>(&Ss[r][k]);
      const float4 w = *reinterpret_cast<const float4*>(&Ws[o][k]);
      acc = fmaf(a.x, w.x, acc);
      acc = fmaf(a.y, w.y, acc);
      acc = fmaf(a.z, w.z, acc);
      acc = fmaf(a.w, w.w, acc);
    }
    C[(row0 + r) * 10 + o] = acc;
  }
}

// ---------------------------------------------------------------------------
// Output LIF scan -> out[t][b][o]. (r8's, unchanged)
// ---------------------------------------------------------------------------
__global__ __launch_bounds__(256) void lif_scan_out(
    const float* __restrict__ cur3, float* __restrict__ out) {
  const int g = blockIdx.x * 256 + threadIdx.x;  // 0..5119
  if (g >= kB * kO) return;
  const int b = g / kO;
  const int o = g - b * kO;
  float m = 0.0f, s = 0.0f;
#pragma unroll 4
  for (int t = 0; t < kT; ++t) {
    const float c = cur3[((size_t)b * kT + t) * kO + o];
    m = __fsub_rn(__fadd_rn(__fmul_rn(kBeta, m), c), s);
    s = (m > kThr) ? 1.0f : 0.0f;
    out[(size_t)t * (kB * kO) + g] = s;
  }
}

extern "C" void kernel_launch(void* const* d_in, const int* in_sizes, int n_in,
                              void* d_out, int out_size, void* d_ws,
                              size_t ws_size, hipStream_t stream) {
  (void)in_sizes;
  (void)n_in;
  (void)out_size;
  (void)ws_size;
  const float* x = (const float*)d_in[0];    // [B,T,784]
  const float* W1 = (const float*)d_in[1];   // [128,784]
  const float* b1 = (const float*)d_in[2];   // [128]
  const float* W2 = (const float*)d_in[3];   // [128,128]
  const float* b2 = (const float*)d_in[4];   // [128]
  const float* W3 = (const float*)d_in[5];   // [10,128]
  const float* b3 = (const float*)d_in[6];   // [10]
  float* out = (float*)d_out;                // [T,B,10] = 4.1 MB

  const size_t bufElems = (size_t)kM * kH;   // 52.4 MB each
  float* P0 = (float*)d_ws;                  // partial0 -> s1 -> cur3
  float* P1 = P0 + bufElems;                 // partial1 -> cur2 -> s2

  // W1T (784x128) + W2T (128x128) = 467 KB stashed at the head of d_out
  // (r10 precedent); lif_scan_out overwrites ALL of d_out at the end.
  float* W1T = out;
  float* W2T = W1T + (size_t)kI * kH;

  transposeW<<<dim3(kI / 16, kH / 16), 256, 0, stream>>>(W1, W1T, kH, kI);
  transposeW<<<dim3(kH / 16, kH / 16), 256, 0, stream>>>(W2, W2T, kH, kH);

  // Layer 1: split-K GEMM, 3200 blocks x 128 threads; scan combines.
  gemm64bt<kI, 1><<<2 * (kM / 64), 128, 0, stream>>>(x, W1T, nullptr, P0,
                                                     bufElems);
  lif_scan13<<<256, 128, 0, stream>>>(P0, P1, b1);
  // Layer 2: full-K GEMM, 1600 blocks.
  gemm64bt<kH, 0><<<kM / 64, 128, 0, stream>>>(P0, W2T, b2, P1, 0);
  lif_scan2<<<256, 128, 0, stream>>>(P1);
  // Layer 3: cur3 -> P0 region (s1 dead).
  gemm3_n10<<<kM / 64, 320, 0, stream>>>(P1, W3, b3, P0);
  lif_scan_out<<<(kB * kO + 255) / 256, 256, 0, stream>>>(P0, out);
}